// Round 5
// baseline (199.352 us; speedup 1.0000x reference)
//
#include <hip/hip_runtime.h>

// Inputs/outputs fp32; internal compute bf16 MFMA (bf16-grade comparison).
// ws layout (64 MB):
//   [0,16M)   Yp    fp32 [B,S,D]
//   [16M,24M) Xb    bf16 [B*S, D]
//   [24M,30M) Wcat  bf16 [3072,1024]
//   [30M,32M) Wob   bf16 [1024,1024]
//   [32M,40M) Qb    bf16 [B,H,S,DK] (post-PE, pre-scaled by 0.125/ln2)
//   [40M,48M) Kraw  bf16 [B,H,S,DK] -> reused as Ab bf16 [B,S,D] after ema_pe
//   [48M,56M) Kp    bf16 packed K-frag order [bh][kt16][c][lane][j8]
//   [56M,64M) Vp    bf16 packed V^T-frag order [bh][kb64][t*4+dn][lane][j4]

#define LB __launch_bounds__(256)
// r6/r8/r15: NO min-waves hint / extra register footprint on attn.
// r10: NO loop-carried MFMA accumulator chains.
// R16: attn = 64-row blocks + LDS double-buffered K/V; uniform 33 steps/block.
// R17/R18/R19 (counter-verified): epilogue register pressure is a first-class
// occupancy knob on the serial GEMM (76 vs 120 VGPR = 41.6 vs 59us); 2-phase
// dbuf at 128^2 is NEUTRAL. Serial-core kernels live off cross-block TLP.
// R20: gemm_qkv -> 256^2 8-phase counted-vmcnt structure (m201 lineage):
//  - 8 waves interleaved at 16-row granularity; phase (mh,nh) reads exactly
//    A-half mh + B-half nh -> halves die cleanly, enabling per-phase staging.
//  - one half-tile staged per phase (2 GLDS/thread); vmcnt(4) at ph4/ph8 only
//    (ledger: slot freed at phase p-1, staged at p, consumed >=4 phases later).
//  - raw s_barrier (asm, memory clobber) -- NOT __syncthreads (vmcnt(0) drain).
//  - G4 swizzle cb ^= (row&7)<<4, both-sides (pre-swizzled source + swz read).
//  - setprio(1) around MFMA cluster (T5; pays only in phase-split schedules).

typedef unsigned short u16;
typedef unsigned int u32;
typedef __attribute__((ext_vector_type(2))) unsigned int u32x2;
typedef __attribute__((ext_vector_type(4))) unsigned short us4;
typedef __attribute__((ext_vector_type(8))) unsigned short us8;
typedef __attribute__((ext_vector_type(8))) __bf16 bf8;
typedef __attribute__((ext_vector_type(4))) float f4;
typedef __attribute__((ext_vector_type(4))) short s4;

// softmax scale folded into Q: exp(s/8) = exp2(s * 0.125/ln2)
#define QSCALE 0.18033688011112042f

#if __has_builtin(__builtin_amdgcn_exp2f)
#define EXP2 __builtin_amdgcn_exp2f   // raw v_exp_f32 (r14-validated: args never denormal)
#else
#define EXP2 exp2f
#endif

static __device__ __forceinline__ float bf2f(u16 h) {
  union { unsigned int u; float f; } c; c.u = ((unsigned int)h) << 16; return c.f;
}
static __device__ __forceinline__ u16 f2bf(float f) {
  union { float f; unsigned int u; } c; c.f = f;
  unsigned int u = c.u + 0x7FFFu + ((c.u >> 16) & 1u);
  return (u16)(u >> 16);
}
// pack 4 fp32 -> 4 bf16 (RNE); packed HW cvt when available
#if __has_builtin(__builtin_amdgcn_cvt_pk_bf16_f32)
typedef __attribute__((ext_vector_type(2))) __bf16 bf2v;
static __device__ __forceinline__ us4 pk_bf16x4(f4 v) {
  bf2v lo = __builtin_amdgcn_cvt_pk_bf16_f32(v[0], v[1]);
  bf2v hi = __builtin_amdgcn_cvt_pk_bf16_f32(v[2], v[3]);
  u32x2 r = {__builtin_bit_cast(u32, lo), __builtin_bit_cast(u32, hi)};
  return __builtin_bit_cast(us4, r);
}
#else
static __device__ __forceinline__ us4 pk_bf16x4(f4 v) {
  return us4{f2bf(v[0]), f2bf(v[1]), f2bf(v[2]), f2bf(v[3])};
}
#endif
static __device__ __forceinline__ float pe_val(int s, int dk) {
  float fr = __expf((float)(dk & ~1) * (-9.210340371976184f / 64.0f));
  float ang = (float)s * fr;
  return (dk & 1) ? __cosf(ang) : __sinf(ang);
}

// 16x16x16 bf16 MFMA, hedged across builtin generations (verified r5).
#if __has_builtin(__builtin_amdgcn_mfma_f32_16x16x16bf16_1k)
static __device__ __forceinline__ f4 mfma16(us4 a, us4 b, f4 c) {
  return __builtin_amdgcn_mfma_f32_16x16x16bf16_1k(
      __builtin_bit_cast(s4, a), __builtin_bit_cast(s4, b), c, 0, 0, 0);
}
#elif __has_builtin(__builtin_amdgcn_mfma_f32_16x16x16_bf16)
typedef __attribute__((ext_vector_type(4))) __bf16 bf4;
static __device__ __forceinline__ f4 mfma16(us4 a, us4 b, f4 c) {
  return __builtin_amdgcn_mfma_f32_16x16x16_bf16(
      __builtin_bit_cast(bf4, a), __builtin_bit_cast(bf4, b), c, 0, 0, 0);
}
#else
static __device__ __forceinline__ f4 mfma16(us4 a, us4 b, f4 c) {
  asm volatile("v_mfma_f32_16x16x16_bf16 %0, %1, %2, %0" : "+v"(c) : "v"(a), "v"(b));
  return c;
}
#endif

#define GLDS(gp, lp) __builtin_amdgcn_global_load_lds( \
    (const __attribute__((address_space(1))) void*)(gp), \
    (__attribute__((address_space(3))) void*)(lp), 16, 0, 0)

#if __has_builtin(__builtin_amdgcn_s_setprio)
#define SETPRIO(n) __builtin_amdgcn_s_setprio(n)
#else
#define SETPRIO(n) asm volatile("s_setprio " #n)
#endif
#define SB       asm volatile("s_barrier" ::: "memory")
#define DRAIN(n) asm volatile("s_waitcnt vmcnt(" #n ")" ::: "memory")

// ---------------- fp32 -> bf16 conversion pre-pass ----------------
__global__ LB void cvt_kernel(const float* __restrict__ X, const float* __restrict__ Wq,
                              const float* __restrict__ Wk, const float* __restrict__ Wv,
                              const float* __restrict__ Wo, u16* __restrict__ Xb,
                              u16* __restrict__ Wcat, u16* __restrict__ Wob) {
  const unsigned t = blockIdx.x * 256 + threadIdx.x;
  const float* src; u16* dst; size_t off;
  if (t < (512u << 10))      { src = X;  dst = Xb;                off = t; }
  else if (t < (640u << 10)) { src = Wq; dst = Wcat;              off = t - (512u << 10); }
  else if (t < (768u << 10)) { src = Wk; dst = Wcat + (1u << 20); off = t - (640u << 10); }
  else if (t < (896u << 10)) { src = Wv; dst = Wcat + (2u << 20); off = t - (768u << 10); }
  else                       { src = Wo; dst = Wob;               off = t - (896u << 10); }
  off *= 8;
  f4 a = *(const f4*)(src + off);
  f4 b = *(const f4*)(src + off + 4);
  us8 o = {f2bf(a[0]), f2bf(a[1]), f2bf(a[2]), f2bf(a[3]),
           f2bf(b[0]), f2bf(b[1]), f2bf(b[2]), f2bf(b[3])};
  *(us8*)(dst + off) = o;
}

// ---------------- 8-phase 256x256 GEMM pieces (R20) ----------------
// Stage one 128x64 bf16 half-tile (16 KB) into linear LDS, source pre-swizzled
// with the involution cb ^= (row&7)<<4 so swizzled ds_reads see correct data.
static __device__ __forceinline__ void stageH(const u16* __restrict__ G, int grow0, int gcol0,
                                              u16* lds, int tid) {
#pragma unroll
  for (int hh = 0; hh < 2; hh++) {
    int c = tid + hh * 512;
    int row = c >> 3, cb = (c & 7) * 16;
    int cbs = cb ^ ((row & 7) << 4);
    GLDS(G + (size_t)(grow0 + row) * 1024 + gcol0 + (cbs >> 1), lds + (size_t)c * 8);
  }
}
// Swizzled fragment read: 8 bf16 at (row, k2*32 + quad*8) of a [128][64] half.
static __device__ __forceinline__ bf8 ldsfrag(const u16* base, int row, int k2, int quad) {
  int cb = (k2 * 64 + quad * 16) ^ ((row & 7) << 4);
  return __builtin_bit_cast(bf8, *(const us8*)(base + row * 64 + (cb >> 1)));
}

// One phase: 12 swizzled ds_reads -> stage one half-tile -> [vmcnt] -> barrier
// -> setprio(1) + 16 MFMA + setprio(0) -> barrier.
#define QPHASE(MH, NH, AH, BH, STAGE, VM) do {                                   \
  bf8 af_[4][2], bv_[2][2];                                                      \
  _Pragma("unroll") for (int q_ = 0; q_ < 4; q_++) {                             \
    int row_ = q_ * 32 + wm * 16 + l16;                                          \
    _Pragma("unroll") for (int k2_ = 0; k2_ < 2; k2_++)                          \
      af_[q_][k2_] = ldsfrag((AH), row_, k2_, quad);                             \
  }                                                                              \
  _Pragma("unroll") for (int j_ = 0; j_ < 2; j_++) {                             \
    int row_ = j_ * 64 + wn * 16 + l16;                                          \
    _Pragma("unroll") for (int k2_ = 0; k2_ < 2; k2_++)                          \
      bv_[j_][k2_] = ldsfrag((BH), row_, k2_, quad);                             \
  }                                                                              \
  STAGE;                                                                         \
  VM;                                                                            \
  SB;                                                                            \
  SETPRIO(1);                                                                    \
  _Pragma("unroll") for (int q_ = 0; q_ < 4; q_++)                               \
    _Pragma("unroll") for (int j_ = 0; j_ < 2; j_++)                             \
      _Pragma("unroll") for (int k2_ = 0; k2_ < 2; k2_++)                        \
        acc[(MH) * 4 + q_][(NH) * 2 + j_] = __builtin_amdgcn_mfma_f32_16x16x32_bf16( \
            af_[q_][k2_], bv_[j_][k2_], acc[(MH) * 4 + q_][(NH) * 2 + j_], 0, 0, 0); \
  SETPRIO(0);                                                                    \
  SB;                                                                            \
} while (0)

// ---------------- QKV projection (fused N=3072), 256^2 8-phase ----------------
__global__ __launch_bounds__(512, 2) void gemm_qkv(
    const u16* __restrict__ Xb, const u16* __restrict__ Wcat,
    u16* __restrict__ Qb, u16* __restrict__ Kraw, u16* __restrict__ Vp) {
  __shared__ u16 LA[2][2][128 * 64];   // [tile parity][half][rows 128][cols 64]
  __shared__ u16 LBs[2][2][128 * 64];
  const int tid = threadIdx.x;
  const int w = tid >> 6, lane = tid & 63;
  const int l16 = lane & 15, quad = lane >> 4;
  const int wm = w & 1, wn = w >> 1;   // 2M x 4N waves, 16-row interleave
  const int m0 = blockIdx.y * 256, n0 = blockIdx.x * 256;

  f4 acc[8][4];
#pragma unroll
  for (int a = 0; a < 8; a++)
#pragma unroll
    for (int b = 0; b < 4; b++) acc[a][b] = f4{0.f, 0.f, 0.f, 0.f};

  // prologue: tile0 (4 halves) + tile1 Ah0/Bh0; tile0 forced complete.
  stageH(Xb,   m0,       0, &LA[0][0][0], tid);
  stageH(Wcat, n0,       0, &LBs[0][0][0], tid);
  stageH(Xb,   m0 + 128, 0, &LA[0][1][0], tid);
  stageH(Wcat, n0 + 128, 0, &LBs[0][1][0], tid);
  stageH(Xb,   m0,      64, &LA[1][0][0], tid);
  stageH(Wcat, n0,      64, &LBs[1][0][0], tid);
  DRAIN(4);
  SB;

  for (int i = 0; i < 8; i++) {
    const int k1  = (2 * i + 1) * 64;        // current T1 col
    const int k2c = (2 * i + 2) * 64;        // T0+2
    const int k3  = (2 * i + 3) * 64;        // T1+2
    const bool s2 = (2 * i + 2) < 16, s3 = (2 * i + 3) < 16;
    // tile T0 = 2i (parity 0)
    QPHASE(0, 0, &LA[0][0][0], &LBs[0][0][0],
           stageH(Xb, m0 + 128, k1, &LA[1][1][0], tid), (void)0);
    QPHASE(0, 1, &LA[0][0][0], &LBs[0][1][0],
           stageH(Wcat, n0 + 128, k1, &LBs[1][1][0], tid), (void)0);
    QPHASE(1, 0, &LA[0][1][0], &LBs[0][0][0],
           { if (s2) stageH(Xb, m0, k2c, &LA[0][0][0], tid); }, (void)0);
    QPHASE(1, 1, &LA[0][1][0], &LBs[0][1][0],
           { if (s2) stageH(Wcat, n0, k2c, &LBs[0][0][0], tid); },
           { if (i == 7) { DRAIN(0); } else { DRAIN(4); } });
    // tile T1 = 2i+1 (parity 1)
    QPHASE(0, 0, &LA[1][0][0], &LBs[1][0][0],
           { if (s2) stageH(Xb, m0 + 128, k2c, &LA[0][1][0], tid); }, (void)0);
    QPHASE(0, 1, &LA[1][0][0], &LBs[1][1][0],
           { if (s2) stageH(Wcat, n0 + 128, k2c, &LBs[0][1][0], tid); }, (void)0);
    QPHASE(1, 0, &LA[1][1][0], &LBs[1][0][0],
           { if (s3) stageH(Xb, m0, k3, &LA[1][0][0], tid); }, (void)0);
    QPHASE(1, 1, &LA[1][1][0], &LBs[1][1][0],
           { if (s3) stageH(Wcat, n0, k3, &LBs[1][0][0], tid); },
           DRAIN(4));
  }

  // epilogue: R19 scalar-store form (low register pressure), re-derived indices.
  const int z = blockIdx.x >> 2;  // 0:Q 1:K 2:V  (n0 range lies in one 1024-block)
#pragma unroll
  for (int mt = 0; mt < 8; mt++)
#pragma unroll
    for (int nt = 0; nt < 4; nt++)
#pragma unroll
      for (int r = 0; r < 4; r++) {
        int m = m0 + mt * 32 + wm * 16 + quad * 4 + r;
        int nn = (n0 + nt * 64 + wn * 16 + l16) & 1023;
        float v = acc[mt][nt][r];
        int b = m >> 11, s = m & 2047, h = nn >> 6, dk = nn & 63;
        size_t bhoff = (size_t)(b * 16 + h) * (2048 * 64);
        if (z == 0) {
          // pre-scale Q: scores exit QK^T already in exp2 domain
          Qb[bhoff + (size_t)s * 64 + dk] = f2bf((v + pe_val(s, dk)) * QSCALE);
        } else if (z == 1) {
          Kraw[bhoff + (size_t)s * 64 + dk] = f2bf(v);
        } else {
          // packed V^T-frag order: [kb64][(t*4+dn)][Q*16+l16][j]
          int kb = s >> 6, sl = s & 63;
          int t = sl >> 4, Qq = (sl >> 2) & 3, jj = sl & 3;
          int dn = dk >> 4, lv = dk & 15;
          Vp[bhoff + (size_t)kb * 4096 + ((t * 4 + dn) * 64 + Qq * 16 + lv) * 4 + jj] = f2bf(v);
        }
      }
}

// ---------------- EMA smear + PE on K; writes packed K-frag order ----------------
__global__ LB void ema_pe(const u16* __restrict__ Kraw, const float* __restrict__ alpha,
                          u16* __restrict__ Kp) {
  int idx = blockIdx.x * 256 + threadIdx.x;
  int b8  = idx & 7;
  int s   = (idx >> 3) & 2047;
  int bh  = idx >> 14;
  int dk8 = b8 * 8;
  size_t base = ((size_t)bh * 2048 + s) * 64 + dk8;
  us8 kc = *(const us8*)(Kraw + base);
  float kv[8];
#pragma unroll
  for (int j = 0; j < 8; j++) kv[j] = bf2f(kc[j]);
  if (s > 0) {
    us8 kp = *(const us8*)(Kraw + base - 64);
    float aa = alpha[(bh & 15) * 2047 + s - 1];
    float a = 1.0f / (1.0f + __expf(-aa));
#pragma unroll
    for (int j = 0; j < 8; j++) kv[j] = kv[j] * a + bf2f(kp[j]) * (1.0f - a);
  }
  us8 o;
#pragma unroll
  for (int j = 0; j < 8; j++) o[j] = f2bf(kv[j] + pe_val(s, dk8 + j));
  int kt16 = s >> 4, c = b8 >> 2, quad = b8 & 3, l16s = s & 15;
  size_t off = (size_t)bh * (2048 * 64) + (size_t)kt16 * 1024 + (c * 64 + quad * 16 + l16s) * 8;
  *(us8*)(Kp + off) = o;
}

// ---------------- causal attention: 64-row blocks, LDS double-buffered K/V ----------------
template<bool MASK>
static __device__ __forceinline__ void attn_step_lds(
    const u16* kbase, const u16* vbase,
    const bf8* qf, f4* acc, float& lsum, int lane, int quad, int qrel0) {
  f4 sc[4];
#pragma unroll
  for (int t = 0; t < 4; t++) sc[t] = f4{0.f, 0.f, 0.f, 0.f};
#pragma unroll
  for (int t = 0; t < 4; t++)
#pragma unroll
    for (int c = 0; c < 2; c++) {
      bf8 kf = __builtin_bit_cast(bf8, *(const us8*)(kbase + (t * 2 + c) * 512 + lane * 8));
      sc[t] = __builtin_amdgcn_mfma_f32_16x16x32_bf16(kf, qf[c], sc[t], 0, 0, 0);
    }
  us4 pf[4];
#pragma unroll
  for (int t = 0; t < 4; t++) {
    f4 pv;
#pragma unroll
    for (int r = 0; r < 4; r++) {
      float s = sc[t][r];
      if (MASK && (t * 16 + quad * 4 + r > qrel0)) s = -1e30f;
      float p = EXP2(s);          // raw v_exp_f32
      lsum += p;
      pv[r] = p;
    }
    pf[t] = pk_bf16x4(pv);
  }
#pragma unroll
  for (int t = 0; t < 4; t++)
#pragma unroll
    for (int dn = 0; dn < 4; dn++) {
      us4 vf = *(const us4*)(vbase + ((t * 4 + dn) * 64 + lane) * 4);
      acc[dn] = mfma16(vf, pf[t], acc[dn]);
    }
}

__global__ LB void attn_kernel(const u16* __restrict__ Qb, const u16* __restrict__ Kp,
                               const u16* __restrict__ Vp, u16* __restrict__ Ab) {
  __shared__ u16 Kls[2][4096];   // double-buffered 64-key K tile (packed frag order)
  __shared__ u16 Vls[2][4096];   // double-buffered 64-key V^T tile
  const int tid = threadIdx.x, w = tid >> 6, lane = tid & 63;
  const int l16 = lane & 15, quad = lane >> 4;
  const int idx = blockIdx.x;
  const int bh = idx & 31;        // XCD locality: each XCD's blocks touch only 4 heads
  const int p  = idx >> 5;        // pair index 0..15
  const size_t bhoff = (size_t)bh * (2048 * 64);
  const u16* Kt = Kp + bhoff;
  const u16* Vt = Vp + bhoff;
  const int b = bh >> 4, h = bh & 15;

  for (int ph = 0; ph < 2; ph++) {
    const int g = ph ? p : 31 - p;   // heavy group first, then light: T sums to 33
    const int T = g + 1;             // number of 64-key steps (last one masked)
    const int qw = g * 64 + w * 16;  // this wave's 16 q-rows

    bf8 qf[2];
#pragma unroll
    for (int c = 0; c < 2; c++)
      qf[c] = __builtin_bit_cast(bf8, *(const us8*)(Qb + bhoff + (size_t)(qw + l16) * 64 + c * 32 + quad * 8));

    f4 acc[4];
#pragma unroll
    for (int dn = 0; dn < 4; dn++) acc[dn] = f4{0.f, 0.f, 0.f, 0.f};
    float lsum = 0.f;

    // prologue: stage kb=0 into buffer 0 (each wave: 2KB of K + 2KB of V, linear)
    {
      const u16* kg = Kt + w * 1024;
      const u16* vg = Vt + w * 1024;
      GLDS(kg + lane * 8,       &Kls[0][w * 1024]);
      GLDS(kg + 512 + lane * 8, &Kls[0][w * 1024 + 512]);
      GLDS(vg + lane * 8,       &Vls[0][w * 1024]);
      GLDS(vg + 512 + lane * 8, &Vls[0][w * 1024 + 512]);
    }
    asm volatile("s_waitcnt vmcnt(0)" ::: "memory");
    __builtin_amdgcn_s_barrier();

    for (int kb = 0; kb < T; kb++) {
      const int cur = kb & 1;
      if (kb + 1 < T) {   // prefetch next tile into the other buffer (overlaps compute)
        const u16* kg = Kt + (size_t)(kb + 1) * 4096 + w * 1024;
        const u16* vg = Vt + (size_t)(kb + 1) * 4096 + w * 1024;
        u16* kl = &Kls[cur ^ 1][w * 1024];
        u16* vl = &Vls[cur ^ 1][w * 1024];
        GLDS(kg + lane * 8, kl);
        GLDS(kg + 512 + lane * 8, kl + 512);
        GLDS(vg + lane * 8, vl);
        GLDS(vg + 512 + lane * 8, vl + 512);
      }
      if (kb == T - 1)
        attn_step_lds<true>(&Kls[cur][0], &Vls[cur][0], qf, acc, lsum, lane, quad, w * 16 + l16);
      else
        attn_step_lds<false>(&Kls[cur][0], &Vls[cur][0], qf, acc, lsum, lane, quad, 0);
      asm volatile("s_waitcnt vmcnt(0)" ::: "memory");  // prefetch landed (had full compute to hide)
      __builtin_amdgcn_s_barrier();                     // all waves done reading buf[cur]
    }

    // epilogue: per-wave softmax denominator (reduce over quads) + store
    lsum += __shfl_xor(lsum, 16, 64);
    lsum += __shfl_xor(lsum, 32, 64);
    float rinv = 1.0f / lsum;
    const int q = qw + l16;
    u16* orow = Ab + ((size_t)(b * 2048 + q)) * 1024 + h * 64;
#pragma unroll
    for (int dn = 0; dn < 4; dn++) {
      us4 o = pk_bf16x4(f4{acc[dn][0] * rinv, acc[dn][1] * rinv,
                           acc[dn][2] * rinv, acc[dn][3] * rinv});
      *(us4*)(orow + dn * 16 + quad * 4) = o;
    }
  }
}

// ---------------- output projection + residual (64x128 tiles, serial core) ----------------
__global__ LB void gemm_out(const u16* __restrict__ Ab, const u16* __restrict__ Wob,
                            const float* __restrict__ X, float* __restrict__ Yp) {
  __shared__ u16 Als[64 * 32];
  __shared__ u16 Bls[128 * 32];
  const int tid = threadIdx.x;
  const int m0 = blockIdx.y * 64, n0 = blockIdx.x * 128;
  const int w = tid >> 6, lane = tid & 63;
  const int l16 = lane & 15, quad = lane >> 4;
  f4 acc[4][2];
#pragma unroll
  for (int a = 0; a < 4; a++)
#pragma unroll
    for (int b = 0; b < 2; b++) acc[a][b] = f4{0.f, 0.f, 0.f, 0.f};

  for (int kk = 0; kk < 1024; kk += 32) {
    __syncthreads();
    {
      int cb = w * 64;
      int c = cb + lane;
      int row = c >> 2, kc = c & 3;
      GLDS(Ab + (size_t)(m0 + row) * 1024 + kk + kc * 8, &Als[cb * 8]);
    }
#pragma unroll
    for (int it = 0; it < 2; it++) {
      int cb = (w * 2 + it) * 64;
      int c = cb + lane;
      int row = c >> 2, kc = c & 3;
      GLDS(Wob + (size_t)(n0 + row) * 1024 + kk + kc * 8, &Bls[cb * 8]);
    }
    __syncthreads();
    bf8 af[4], bfr[2];
#pragma unroll
    for (int mt = 0; mt < 4; mt++)
      af[mt] = __builtin_bit_cast(bf8, *(const us8*)(&Als[(mt * 16 + l16) * 32 + quad * 8]));
#pragma unroll
    for (int nt = 0; nt < 2; nt++)
      bfr[nt] = __builtin_bit_cast(bf8, *(const us8*)(&Bls[(w * 32 + nt * 16 + l16) * 32 + quad * 8]));
#pragma unroll
    for (int mt = 0; mt < 4; mt++)
#pragma unroll
      for (int nt = 0; nt < 2; nt++)
        acc[mt][nt] = __builtin_amdgcn_mfma_f32_16x16x32_bf16(af[mt], bfr[nt], acc[mt][nt], 0, 0, 0);
  }

#pragma unroll
  for (int mt = 0; mt < 4; mt++)
#pragma unroll
    for (int nt = 0; nt < 2; nt++)
#pragma unroll
      for (int r = 0; r < 4; r++) {
        int m = m0 + mt * 16 + quad * 4 + r;
        int n = n0 + w * 32 + nt * 16 + l16;
        size_t o = (size_t)m * 1024 + n;
        Yp[o] = acc[mt][nt][r] + X[o];
      }
}

// ---------------- LayerNorm ----------------
__global__ LB void ln_kernel(const float* __restrict__ Y, const float* __restrict__ g,
                             const float* __restrict__ bta, float* __restrict__ out) {
  __shared__ float ls[4], lsq[4];
  const int row = blockIdx.x, tid = threadIdx.x;
  const int w = tid >> 6, lane = tid & 63;
  f4 v = *(const f4*)(Y + (size_t)row * 1024 + tid * 4);
  float s  = v[0] + v[1] + v[2] + v[3];
  float sq = v[0] * v[0] + v[1] * v[1] + v[2] * v[2] + v[3] * v[3];
#pragma unroll
  for (int d = 1; d < 64; d <<= 1) { s += __shfl_xor(s, d, 64); sq += __shfl_xor(sq, d, 64); }
  if (lane == 0) { ls[w] = s; lsq[w] = sq; }
  __syncthreads();
  s  = ls[0] + ls[1] + ls[2] + ls[3];
  sq = lsq[0] + lsq[1] + lsq[2] + lsq[3];
  float mu  = s * (1.0f / 1024.0f);
  float var = sq * (1.0f / 1024.0f) - mu * mu;
  float rs  = rsqrtf(var + 1e-5f);
  f4 o;
#pragma unroll
  for (int j = 0; j < 4; j++) {
    int col = tid * 4 + j;
    o[j] = (v[j] - mu) * rs * g[col] + bta[col];
  }
  *(f4*)(out + (size_t)row * 1024 + tid * 4) = o;
}

extern "C" void kernel_launch(void* const* d_in, const int* in_sizes, int n_in,
                              void* d_out, int out_size, void* d_ws, size_t ws_size,
                              hipStream_t stream) {
  (void)in_sizes; (void)n_in; (void)out_size; (void)ws_size;
  const float* X  = (const float*)d_in[0];
  const float* Wq = (const float*)d_in[1];
  const float* Wk = (const float*)d_in[2];
  const float* Wv = (const float*)d_in[3];
  const float* Wo = (const float*)d_in[4];
  const float* al = (const float*)d_in[5];
  const float* g  = (const float*)d_in[6];
  const float* bt = (const float*)d_in[7];

  char* ws = (char*)d_ws;
  float* Yp   = (float*)(ws);
  u16*   Xb   = (u16*)(ws + ((size_t)16 << 20));
  u16*   Wcat = (u16*)(ws + ((size_t)24 << 20));
  u16*   Wob  = (u16*)(ws + ((size_t)30 << 20));
  u16*   Qb   = (u16*)(ws + ((size_t)32 << 20));
  u16*   Kraw = (u16*)(ws + ((size_t)40 << 20));
  u16*   Ab   = (u16*)(ws + ((size_t)40 << 20));  // reuses Kraw
  u16*   Kp   = (u16*)(ws + ((size_t)48 << 20));
  u16*   Vp   = (u16*)(ws + ((size_t)56 << 20));

  cvt_kernel<<<dim3(4096), 256, 0, stream>>>(X, Wq, Wk, Wv, Wo, Xb, Wcat, Wob);
  gemm_qkv<<<dim3(12, 16), 512, 0, stream>>>(Xb, Wcat, Qb, Kraw, Vp);
  ema_pe<<<dim3(2048), 256, 0, stream>>>(Kraw, al, Kp);
  attn_kernel<<<dim3(512), 256, 0, stream>>>(Qb, Kp, Vp, Ab);
  gemm_out<<<dim3(8, 64), 256, 0, stream>>>(Ab, Wob, X, Yp);
  ln_kernel<<<dim3(4096), 256, 0, stream>>>(Yp, g, bt, (float*)d_out);
}